// Round 5
// baseline (281.239 us; speedup 1.0000x reference)
//
#include <hip/hip_runtime.h>
#include <hip/hip_fp16.h>

#define NN 50000
#define EE 800000
#define NB_E2 1563       // ceil(400000/256): 2 edges/thread grids (k_edge)
#define NB_CNT 782       // ceil(200000/256): 4 edges/thread (k_count)
#define NWIN 4           // windows (XCD pairs): csr seg ~800KB fits per-XCD L2
#define WIN 12500        // node-window per slot (4 * 12500 = 50000)
#define EPB 1024         // edges per fill chunk (256 thr x 4)
#define NCHUNK 782       // ceil(800000/1024)
#define NFILL (NCHUNK * NWIN)   // 3128 fill blocks
#define NGEMM 588        // 196 row-blocks x 3 grp

// ---------------- degree count + packed (rank<<16 | col), 4 edges/thread ----------------
// col < 50000 < 2^16, rank < max-degree (~45) < 2^16
__global__ void k_count(const int* __restrict__ ei, int* cnt, unsigned* __restrict__ pk) {
    int t = blockIdx.x * 256 + threadIdx.x;
    int base = t * 4;
    if (base + 3 < EE) {
        int4 cc = *(const int4*)(ei + EE + base);
        unsigned r0 = (unsigned)atomicAdd(&cnt[cc.x], 1);
        unsigned r1 = (unsigned)atomicAdd(&cnt[cc.y], 1);
        unsigned r2 = (unsigned)atomicAdd(&cnt[cc.z], 1);
        unsigned r3 = (unsigned)atomicAdd(&cnt[cc.w], 1);
        *(uint4*)(pk + base) = make_uint4((unsigned)cc.x | (r0 << 16),
                                          (unsigned)cc.y | (r1 << 16),
                                          (unsigned)cc.z | (r2 << 16),
                                          (unsigned)cc.w | (r3 << 16));
    } else {
        for (int e = 0; e < 4; e++) {
            int tt = base + e;
            if (tt < EE) {
                int c = ei[EE + tt];
                unsigned r = (unsigned)atomicAdd(&cnt[c], 1);
                pk[tt] = (unsigned)c | (r << 16);
            }
        }
    }
}

// ---------------- fused scan: local scan + direct global prefix (1 dispatch) ----------------
// Each block sums cnt[0 .. b*256) itself (<=195KB L2-hit int4 reads) instead of the
// bsum two-pass; removes one dispatch + gap.
__global__ void k_scan(const int* __restrict__ cnt, float* __restrict__ dis,
                       int2* __restrict__ sd, int* __restrict__ starts, int n) {
    __shared__ int s[256];
    int tid = threadIdx.x, b = blockIdx.x;
    int i = b * 256 + tid;
    int v = (i < n) ? cnt[i] : 0;
    if (i < n) dis[i] = rsqrtf((float)v + 1.0f);  // +1 self loop
    s[tid] = v;
    __syncthreads();
    for (int off = 1; off < 256; off <<= 1) {
        int t2 = (tid >= off) ? s[tid - off] : 0;
        __syncthreads();
        if (tid >= off) s[tid] += t2;
        __syncthreads();
    }
    int loc = s[tid] - v;   // block-local exclusive
    // global prefix: sum of cnt over preceding blocks
    int lim = b * 256;
    int pre = 0;
    for (int j = tid * 4; j < lim; j += 1024) {
        int4 c4 = *(const int4*)(cnt + j);
        pre += c4.x + c4.y + c4.z + c4.w;
    }
    __syncthreads();
    s[tid] = pre;
    __syncthreads();
    for (int off = 128; off; off >>= 1) {
        if (tid < off) s[tid] += s[tid + off];
        __syncthreads();
    }
    int boff = s[0];
    if (i < n) {
        int st = loc + boff;
        sd[i] = make_int2(st, v);
        starts[i] = st;
    }
}

// ---------------- shared GEMM body (layer1 fused into fill dispatch; layer2 standalone) ----------------
__device__ __forceinline__ void gemm_body(
    float* xt, int bx, int grp,
    const float* __restrict__ x, const float* __restrict__ Wb,
    const float* __restrict__ Wc, const float* __restrict__ bc,
    const float* __restrict__ dis,
    __half* __restrict__ bsh, float* __restrict__ wcomb, int n)
{
    int tid = threadIdx.x;
    int row0 = bx * 256;
    int row = row0 + tid;
    bool valid = row < n;

    const float* W = (grp < 2) ? (Wb + grp * 32) : Wc;
    const int ldw = (grp < 2) ? 64 : 32;

    float acc[32];
#pragma unroll
    for (int c = 0; c < 32; c++) acc[c] = 0.f;

    for (int s = 0; s < 4; s++) {
        int base_k = s * 32;
        float4 v[8];
#pragma unroll
        for (int i = 0; i < 8; i++) {
            int idx = i * 256 + tid;
            int r = idx >> 3;
            int k4 = idx & 7;
            int gr = row0 + r;
            v[i] = (gr < n) ? *(const float4*)(x + (size_t)gr * 128 + base_k + k4 * 4)
                            : make_float4(0.f, 0.f, 0.f, 0.f);
        }
        __syncthreads();
#pragma unroll
        for (int i = 0; i < 8; i++) {
            int idx = i * 256 + tid;
            int r = idx >> 3;
            int k4 = idx & 7;
            xt[(k4 * 4 + 0) * 257 + r] = v[i].x;
            xt[(k4 * 4 + 1) * 257 + r] = v[i].y;
            xt[(k4 * 4 + 2) * 257 + r] = v[i].z;
            xt[(k4 * 4 + 3) * 257 + r] = v[i].w;
        }
        __syncthreads();

        const float* Ws = W + base_k * ldw;
#pragma unroll 8
        for (int k = 0; k < 32; k++) {
            float xs = xt[k * 257 + tid];
            const float* wk = Ws + k * ldw;
#pragma unroll
            for (int c = 0; c < 32; c++) acc[c] = fmaf(xs, wk[c], acc[c]);
        }
    }

    if (!valid) return;
    if (grp < 2) {
        float d = dis[row];
        __half2 hh[16];
#pragma unroll
        for (int c = 0; c < 16; c++)
            hh[c] = __floats2half2_rn(acc[2 * c] * d, acc[2 * c + 1] * d);
        uint4* bo = (uint4*)(bsh + (size_t)row * 64 + grp * 32);
        const uint4* src = (const uint4*)hh;
#pragma unroll
        for (int c = 0; c < 4; c++) bo[c] = src[c];
    } else {
        float4* wo = (float4*)(wcomb + (size_t)row * 32);
#pragma unroll
        for (int c = 0; c < 8; c++)
            wo[c] = make_float4(acc[4*c] + bc[4*c], acc[4*c+1] + bc[4*c+1],
                                acc[4*c+2] + bc[4*c+2], acc[4*c+3] + bc[4*c+3]);
    }
}

// ---------------- fused: CSR fill (windowed, atomic-free) PARALLEL WITH conv1 GEMM ----------------
// fill depends on starts/pk; gemm1 depends on x/dis — independent, share one dispatch.
// Blocks [0,NFILL): fill, window = blockIdx&3 (XCD pairing preserved).
// Blocks [NFILL, NFILL+NGEMM): gemm1; grp-major adjacency (b2%3) -> x rows reused 3x in L2.
__global__ __launch_bounds__(256) void k_fillgemm(
    const int* __restrict__ ei, const unsigned* __restrict__ pk,
    const int* __restrict__ starts, int* __restrict__ csr,
    const float* __restrict__ x, const float* __restrict__ Wb,
    const float* __restrict__ Wc, const float* __restrict__ bc,
    const float* __restrict__ dis,
    __half* __restrict__ bsh, float* __restrict__ wcomb, int n)
{
    __shared__ float xt[32 * 257];
    if (blockIdx.x < NFILL) {
        int w = blockIdx.x & (NWIN - 1);
        int chunk = blockIdx.x >> 2;
        int base = chunk * EPB + threadIdx.x * 4;
        unsigned lo = w * WIN, hi = lo + WIN;
        if (base + 3 < EE) {
            int4 rr = *(const int4*)(ei + base);
            uint4 pp = *(const uint4*)(pk + base);
            unsigned c0 = pp.x & 0xffffu, c1 = pp.y & 0xffffu;
            unsigned c2 = pp.z & 0xffffu, c3 = pp.w & 0xffffu;
            if (c0 >= lo && c0 < hi) csr[starts[c0] + (pp.x >> 16)] = rr.x;
            if (c1 >= lo && c1 < hi) csr[starts[c1] + (pp.y >> 16)] = rr.y;
            if (c2 >= lo && c2 < hi) csr[starts[c2] + (pp.z >> 16)] = rr.z;
            if (c3 >= lo && c3 < hi) csr[starts[c3] + (pp.w >> 16)] = rr.w;
        } else {
            for (int e = 0; e < 4; e++) {
                int t = base + e;
                if (t < EE) {
                    unsigned pv = pk[t];
                    unsigned c = pv & 0xffffu;
                    if (c >= lo && c < hi) csr[starts[c] + (pv >> 16)] = ei[t];
                }
            }
        }
        return;
    }
    int b2 = blockIdx.x - NFILL;
    gemm_body(xt, b2 / 3, b2 % 3, x, Wb, Wc, bc, dis, bsh, wcomb, n);
}

// ---------------- standalone GEMM (layer 2) ----------------
__global__ __launch_bounds__(256) void k_gemm(
    const float* __restrict__ x, const float* __restrict__ Wb,
    const float* __restrict__ Wc, const float* __restrict__ bc,
    const float* __restrict__ dis,
    __half* __restrict__ bsh, float* __restrict__ wcomb, int n)
{
    __shared__ float xt[32 * 257];
    gemm_body(xt, blockIdx.x, blockIdx.y, x, Wb, Wc, bc, dis, bsh, wcomb, n);
}

// ---------------- fused aggregate (fp16 gather, pipelined, 8 edges/iter) + combine ----------------
template<int LAYER2>
__global__ __launch_bounds__(256) void k_agg(
    const int* __restrict__ csr, const int2* __restrict__ sd,
    const __half* __restrict__ bsh, const float* __restrict__ dis,
    const float* __restrict__ wcomb, const float* __restrict__ bias,
    float* __restrict__ h,
    const float* __restrict__ Wcls, const float* __restrict__ bcls,
    float* __restrict__ p, int n)
{
    int wid = (blockIdx.x * 256 + threadIdx.x) >> 6;
    int lane = threadIdx.x & 63;
    if (wid >= n) return;
    int2 s2 = sd[wid];
    int start = s2.x, deg = s2.y;
    int g = lane >> 4, q = lane & 15;

    const uint2* bsp = (const uint2*)bsh;
    float4 acc4 = make_float4(0.f, 0.f, 0.f, 0.f);
    if (g == 0) {  // self-loop term (pre-scaled)
        uint2 v = bsp[(size_t)wid * 16 + q];
        float2 lo = __half22float2(*(const __half2*)&v.x);
        float2 hi = __half22float2(*(const __half2*)&v.y);
        acc4 = make_float4(lo.x, lo.y, hi.x, hi.y);
    }

    int j = 0;
    int ia = 0, ib = 0;
    if (8 <= deg) { ia = csr[start + g]; ib = csr[start + 4 + g]; }
    while (j + 8 <= deg) {
        int jn = j + 8;
        int na = 0, nb = 0;
        if (jn + 8 <= deg) { na = csr[start + jn + g]; nb = csr[start + jn + 4 + g]; }
        uint2 v0 = bsp[(size_t)ia * 16 + q];
        uint2 v1 = bsp[(size_t)ib * 16 + q];
        float2 l0 = __half22float2(*(const __half2*)&v0.x);
        float2 h0 = __half22float2(*(const __half2*)&v0.y);
        float2 l1 = __half22float2(*(const __half2*)&v1.x);
        float2 h1 = __half22float2(*(const __half2*)&v1.y);
        acc4.x += l0.x + l1.x;
        acc4.y += l0.y + l1.y;
        acc4.z += h0.x + h1.x;
        acc4.w += h0.y + h1.y;
        ia = na; ib = nb; j = jn;
    }
    int last = start + deg - 1;
    for (; j < deg; j += 4) {
        int idx = start + j + g;
        int r = csr[min(idx, last)];
        uint2 v = bsp[(size_t)r * 16 + q];
        float2 lo = __half22float2(*(const __half2*)&v.x);
        float2 hi = __half22float2(*(const __half2*)&v.y);
        float m = (j + g < deg) ? 1.f : 0.f;
        acc4.x = fmaf(lo.x, m, acc4.x);
        acc4.y = fmaf(lo.y, m, acc4.y);
        acc4.z = fmaf(hi.x, m, acc4.z);
        acc4.w = fmaf(hi.y, m, acc4.w);
    }

    acc4.x += __shfl_xor(acc4.x, 16, 64);
    acc4.y += __shfl_xor(acc4.y, 16, 64);
    acc4.z += __shfl_xor(acc4.z, 16, 64);
    acc4.w += __shfl_xor(acc4.w, 16, 64);
    acc4.x += __shfl_xor(acc4.x, 32, 64);
    acc4.y += __shfl_xor(acc4.y, 32, 64);
    acc4.z += __shfl_xor(acc4.z, 32, 64);
    acc4.w += __shfl_xor(acc4.w, 32, 64);

    float d = dis[wid];
    acc4.x *= d; acc4.y *= d; acc4.z *= d; acc4.w *= d;

    int src = lane >> 2;
    float t0 = __shfl(acc4.x, src, 64);
    float t1 = __shfl(acc4.y, src, 64);
    float t2 = __shfl(acc4.z, src, 64);
    float t3 = __shfl(acc4.w, src, 64);
    int c = lane & 3;
    float acc = (c == 0) ? t0 : (c == 1) ? t1 : (c == 2) ? t2 : t3;

    int fh = lane & 15;
    float a0 = __shfl(acc, fh, 64);
    float a1 = __shfl(acc, 16 + fh, 64);
    float a2 = __shfl(acc, 32 + fh, 64);
    float a3 = __shfl(acc, 48 + fh, 64);
    const float* wn = wcomb + (size_t)wid * 32;
    int hd = lane >> 4;
    float s1 = bias[lane];
    float s2v = bias[64 + lane];
    s1 = fmaf(wn[hd * 4 + 0], a0, s1);
    s1 = fmaf(wn[hd * 4 + 1], a1, s1);
    s1 = fmaf(wn[hd * 4 + 2], a2, s1);
    s1 = fmaf(wn[hd * 4 + 3], a3, s1);
    s2v = fmaf(wn[(4 + hd) * 4 + 0], a0, s2v);
    s2v = fmaf(wn[(4 + hd) * 4 + 1], a1, s2v);
    s2v = fmaf(wn[(4 + hd) * 4 + 2], a2, s2v);
    s2v = fmaf(wn[(4 + hd) * 4 + 3], a3, s2v);

    if (!LAYER2) {
        s1 = fmaxf(s1, 0.f);
        s2v = fmaxf(s2v, 0.f);
        h[(size_t)wid * 128 + lane] = s1;
        h[(size_t)wid * 128 + 64 + lane] = s2v;
    } else {
        float r0 = s1 * Wcls[lane * 2 + 0] + s2v * Wcls[(64 + lane) * 2 + 0];
        float r1 = s1 * Wcls[lane * 2 + 1] + s2v * Wcls[(64 + lane) * 2 + 1];
        float r2 = s1 * Wcls[(128 + lane) * 2 + 0] + s2v * Wcls[(192 + lane) * 2 + 0];
        float r3 = s1 * Wcls[(128 + lane) * 2 + 1] + s2v * Wcls[(192 + lane) * 2 + 1];
#pragma unroll
        for (int off = 32; off; off >>= 1) {
            r0 += __shfl_xor(r0, off, 64);
            r1 += __shfl_xor(r1, off, 64);
            r2 += __shfl_xor(r2, off, 64);
            r3 += __shfl_xor(r3, off, 64);
        }
        if (lane == 0) {
            p[wid * 4 + 0] = r0 + bcls[0];
            p[wid * 4 + 1] = r1 + bcls[1];
            p[wid * 4 + 2] = r2;
            p[wid * 4 + 3] = r3;
        }
    }
}

// ---------------- edge output: 2 edges/thread ----------------
__global__ void k_edge(const int* __restrict__ ei, const float* __restrict__ p,
                       float* __restrict__ out)
{
    int t = blockIdx.x * blockDim.x + threadIdx.x;
    if (t >= EE / 2) return;
    int2 rr = *(const int2*)(ei + 2 * t);
    int2 cc = *(const int2*)(ei + EE + 2 * t);
    float2 pt0 = *(const float2*)(p + rr.x * 4);
    float2 pt1 = *(const float2*)(p + rr.y * 4);
    float2 pb0 = *(const float2*)(p + cc.x * 4 + 2);
    float2 pb1 = *(const float2*)(p + cc.y * 4 + 2);
    float4 o;
    o.x = pt0.x + pb0.x;
    o.y = pt0.y + pb0.y;
    o.z = pt1.x + pb1.x;
    o.w = pt1.y + pb1.y;
    *(float4*)(out + (size_t)t * 4) = o;
}

extern "C" void kernel_launch(void* const* d_in, const int* in_sizes, int n_in,
                              void* d_out, int out_size, void* d_ws, size_t ws_size,
                              hipStream_t stream) {
    const float* x    = (const float*)d_in[0];
    const int*   ei   = (const int*)d_in[1];
    const float* Wb1  = (const float*)d_in[2];
    const float* Wc1  = (const float*)d_in[3];
    const float* bc1  = (const float*)d_in[4];
    const float* b1   = (const float*)d_in[5];
    const float* Wb2  = (const float*)d_in[6];
    const float* Wc2  = (const float*)d_in[7];
    const float* bc2  = (const float*)d_in[8];
    const float* b2   = (const float*)d_in[9];
    const float* Wcls = (const float*)d_in[10];
    const float* bcls = (const float*)d_in[11];
    float* out = (float*)d_out;

    char* ws = (char*)d_ws;
    size_t off = 0;
    auto alloc = [&](size_t bytes) {
        void* pp = ws + off;
        off += (bytes + 15) & ~(size_t)15;
        return pp;
    };

    float*    dis    = (float*)alloc(50048 * 4);
    __half*   bsh    = (__half*)alloc((size_t)NN * 64 * 2);
    float*    wcomb  = (float*)alloc((size_t)NN * 32 * 4);
    float*    h      = (float*)alloc((size_t)NN * 128 * 4);
    float*    p      = (float*)alloc((size_t)NN * 4 * 4);
    int*      cnt    = (int*)alloc(50048 * 4);
    int*      starts = (int*)alloc(50048 * 4);
    int2*     sd     = (int2*)alloc((size_t)50048 * 8);
    int*      csr    = (int*)alloc((size_t)EE * 4);
    unsigned* pk     = (unsigned*)alloc((size_t)EE * 4);

    const int B = 256;
    int gN   = (NN + B - 1) / B;   // 196
    int gN64 = (NN * 64) / B;      // 12500
    dim3 gG(gN, 3);

    // CSR build + conv1 GEMM overlap:
    hipMemsetAsync(cnt, 0, NN * sizeof(int), stream);
    k_count<<<NB_CNT, B, 0, stream>>>(ei, cnt, pk);
    k_scan<<<gN, B, 0, stream>>>(cnt, dis, sd, starts, NN);
    k_fillgemm<<<NFILL + NGEMM, B, 0, stream>>>(ei, pk, starts, csr,
                                                x, Wb1, Wc1, bc1, dis, bsh, wcomb, NN);

    // conv1 aggregate
    k_agg<0><<<gN64, B, 0, stream>>>(csr, sd, bsh, dis, wcomb, b1, h,
                                     Wcls, bcls, p, NN);

    // conv2 (+ fused edge-cls projection)
    k_gemm<<<gG, B, 0, stream>>>(h, Wb2, Wc2, bc2, dis, bsh, wcomb, NN);
    k_agg<1><<<gN64, B, 0, stream>>>(csr, sd, bsh, dis, wcomb, b2, h,
                                     Wcls, bcls, p, NN);

    // edge output
    k_edge<<<NB_E2, B, 0, stream>>>(ei, p, out);
}

// Round 6
// 280.635 us; speedup vs baseline: 1.0022x; 1.0022x over previous
//
#include <hip/hip_runtime.h>
#include <hip/hip_fp16.h>

#define NN 50000
#define EE 800000
#define NB_E2 1563       // ceil(400000/256): 2 edges/thread grids (k_edge)
#define NB_CNT 782       // ceil(200000/256): 4 edges/thread (k_count)
#define NWIN 2           // windows: csr seg ~1.6MB, accumulated across 4 XCD L2s each
#define WIN 25000        // node-window per slot (2 * 25000 = 50000)
#define EPB 1024         // edges per fill chunk (256 thr x 4)
#define NCHUNK 782       // ceil(800000/1024)

// ---------------- degree count + packed (rank<<16 | col), 4 edges/thread ----------------
// col < 50000 < 2^16, rank < max-degree (~45) < 2^16
__global__ void k_count(const int* __restrict__ ei, int* cnt, unsigned* __restrict__ pk) {
    int t = blockIdx.x * 256 + threadIdx.x;
    int base = t * 4;
    if (base + 3 < EE) {
        int4 cc = *(const int4*)(ei + EE + base);
        unsigned r0 = (unsigned)atomicAdd(&cnt[cc.x], 1);
        unsigned r1 = (unsigned)atomicAdd(&cnt[cc.y], 1);
        unsigned r2 = (unsigned)atomicAdd(&cnt[cc.z], 1);
        unsigned r3 = (unsigned)atomicAdd(&cnt[cc.w], 1);
        *(uint4*)(pk + base) = make_uint4((unsigned)cc.x | (r0 << 16),
                                          (unsigned)cc.y | (r1 << 16),
                                          (unsigned)cc.z | (r2 << 16),
                                          (unsigned)cc.w | (r3 << 16));
    } else {
        for (int e = 0; e < 4; e++) {
            int tt = base + e;
            if (tt < EE) {
                int c = ei[EE + tt];
                unsigned r = (unsigned)atomicAdd(&cnt[c], 1);
                pk[tt] = (unsigned)c | (r << 16);
            }
        }
    }
}

// ---------------- fused scan: local scan + direct global prefix (1 dispatch) ----------------
__global__ void k_scan(const int* __restrict__ cnt, float* __restrict__ dis,
                       int2* __restrict__ sd, int* __restrict__ starts, int n) {
    __shared__ int s[256];
    int tid = threadIdx.x, b = blockIdx.x;
    int i = b * 256 + tid;
    int v = (i < n) ? cnt[i] : 0;
    if (i < n) dis[i] = rsqrtf((float)v + 1.0f);  // +1 self loop
    s[tid] = v;
    __syncthreads();
    for (int off = 1; off < 256; off <<= 1) {
        int t2 = (tid >= off) ? s[tid - off] : 0;
        __syncthreads();
        if (tid >= off) s[tid] += t2;
        __syncthreads();
    }
    int loc = s[tid] - v;   // block-local exclusive
    // global prefix: sum of cnt over preceding blocks (L2-hit int4 reads)
    int lim = b * 256;
    int pre = 0;
    for (int j = tid * 4; j < lim; j += 1024) {
        int4 c4 = *(const int4*)(cnt + j);
        pre += c4.x + c4.y + c4.z + c4.w;
    }
    __syncthreads();
    s[tid] = pre;
    __syncthreads();
    for (int off = 128; off; off >>= 1) {
        if (tid < off) s[tid] += s[tid + off];
        __syncthreads();
    }
    int boff = s[0];
    if (i < n) {
        int st = loc + boff;
        sd[i] = make_int2(st, v);
        starts[i] = st;
    }
}

// ---------------- CSR fill: atomic-free, windowed scatter, packed reads ----------------
// 2 windows: reads row(4B)+pk(4B) per edge per window = 12.8MB total.
// Window w served by blocks blockIdx%2==w -> XCDs {w,w+2,w+4,w+6}; csr window
// segment ~1.6MB accumulates in those 4 L2s, byte-masked writeback on eviction.
__global__ __launch_bounds__(256) void k_fill(
    const int* __restrict__ ei, const unsigned* __restrict__ pk,
    const int* __restrict__ starts, int* __restrict__ csr)
{
    int w = blockIdx.x & (NWIN - 1);
    int chunk = blockIdx.x >> 1;
    int base = chunk * EPB + threadIdx.x * 4;
    unsigned lo = w * WIN, hi = lo + WIN;
    if (base + 3 < EE) {
        int4 rr = *(const int4*)(ei + base);
        uint4 pp = *(const uint4*)(pk + base);
        unsigned c0 = pp.x & 0xffffu, c1 = pp.y & 0xffffu;
        unsigned c2 = pp.z & 0xffffu, c3 = pp.w & 0xffffu;
        if (c0 >= lo && c0 < hi) csr[starts[c0] + (pp.x >> 16)] = rr.x;
        if (c1 >= lo && c1 < hi) csr[starts[c1] + (pp.y >> 16)] = rr.y;
        if (c2 >= lo && c2 < hi) csr[starts[c2] + (pp.z >> 16)] = rr.z;
        if (c3 >= lo && c3 < hi) csr[starts[c3] + (pp.w >> 16)] = rr.w;
    } else {
        for (int e = 0; e < 4; e++) {
            int t = base + e;
            if (t < EE) {
                unsigned pv = pk[t];
                unsigned c = pv & 0xffffu;
                if (c >= lo && c < hi) csr[starts[c] + (pv >> 16)] = ei[t];
            }
        }
    }
}

// ---------------- GEMM: LDS-staged x, thread-per-row, W via scalar cache ----------------
__global__ __launch_bounds__(256) void k_gemm(
    const float* __restrict__ x, const float* __restrict__ Wb,
    const float* __restrict__ Wc, const float* __restrict__ bc,
    const float* __restrict__ dis,
    __half* __restrict__ bsh, float* __restrict__ wcomb, int n)
{
    __shared__ float xt[32 * 257];  // transposed tile: xt[k][row]
    int tid = threadIdx.x;
    int grp = blockIdx.y;
    int row0 = blockIdx.x * 256;
    int row = row0 + tid;
    bool valid = row < n;

    const float* W = (grp < 2) ? (Wb + grp * 32) : Wc;
    const int ldw = (grp < 2) ? 64 : 32;

    float acc[32];
#pragma unroll
    for (int c = 0; c < 32; c++) acc[c] = 0.f;

    for (int s = 0; s < 4; s++) {
        int base_k = s * 32;
        float4 v[8];
#pragma unroll
        for (int i = 0; i < 8; i++) {
            int idx = i * 256 + tid;
            int r = idx >> 3;
            int k4 = idx & 7;
            int gr = row0 + r;
            v[i] = (gr < n) ? *(const float4*)(x + (size_t)gr * 128 + base_k + k4 * 4)
                            : make_float4(0.f, 0.f, 0.f, 0.f);
        }
        __syncthreads();
#pragma unroll
        for (int i = 0; i < 8; i++) {
            int idx = i * 256 + tid;
            int r = idx >> 3;
            int k4 = idx & 7;
            xt[(k4 * 4 + 0) * 257 + r] = v[i].x;
            xt[(k4 * 4 + 1) * 257 + r] = v[i].y;
            xt[(k4 * 4 + 2) * 257 + r] = v[i].z;
            xt[(k4 * 4 + 3) * 257 + r] = v[i].w;
        }
        __syncthreads();

        const float* Ws = W + base_k * ldw;
#pragma unroll 8
        for (int k = 0; k < 32; k++) {
            float xs = xt[k * 257 + tid];
            const float* wk = Ws + k * ldw;
#pragma unroll
            for (int c = 0; c < 32; c++) acc[c] = fmaf(xs, wk[c], acc[c]);
        }
    }

    if (!valid) return;
    if (grp < 2) {
        float d = dis[row];
        __half2 hh[16];
#pragma unroll
        for (int c = 0; c < 16; c++)
            hh[c] = __floats2half2_rn(acc[2 * c] * d, acc[2 * c + 1] * d);
        uint4* bo = (uint4*)(bsh + (size_t)row * 64 + grp * 32);
        const uint4* src = (const uint4*)hh;
#pragma unroll
        for (int c = 0; c < 4; c++) bo[c] = src[c];
    } else {
        float4* wo = (float4*)(wcomb + (size_t)row * 32);
#pragma unroll
        for (int c = 0; c < 8; c++)
            wo[c] = make_float4(acc[4*c] + bc[4*c], acc[4*c+1] + bc[4*c+1],
                                acc[4*c+2] + bc[4*c+2], acc[4*c+3] + bc[4*c+3]);
    }
}

// ---------------- fused aggregate (fp16 gather, pipelined, 8 edges/iter) + combine ----------------
template<int LAYER2>
__global__ __launch_bounds__(256) void k_agg(
    const int* __restrict__ csr, const int2* __restrict__ sd,
    const __half* __restrict__ bsh, const float* __restrict__ dis,
    const float* __restrict__ wcomb, const float* __restrict__ bias,
    float* __restrict__ h,
    const float* __restrict__ Wcls, const float* __restrict__ bcls,
    float* __restrict__ p, int n)
{
    int wid = (blockIdx.x * 256 + threadIdx.x) >> 6;
    int lane = threadIdx.x & 63;
    if (wid >= n) return;
    int2 s2 = sd[wid];
    int start = s2.x, deg = s2.y;
    int g = lane >> 4, q = lane & 15;

    const uint2* bsp = (const uint2*)bsh;
    float4 acc4 = make_float4(0.f, 0.f, 0.f, 0.f);
    if (g == 0) {  // self-loop term (pre-scaled)
        uint2 v = bsp[(size_t)wid * 16 + q];
        float2 lo = __half22float2(*(const __half2*)&v.x);
        float2 hi = __half22float2(*(const __half2*)&v.y);
        acc4 = make_float4(lo.x, lo.y, hi.x, hi.y);
    }

    int j = 0;
    int ia = 0, ib = 0;
    if (8 <= deg) { ia = csr[start + g]; ib = csr[start + 4 + g]; }
    while (j + 8 <= deg) {
        int jn = j + 8;
        int na = 0, nb = 0;
        if (jn + 8 <= deg) { na = csr[start + jn + g]; nb = csr[start + jn + 4 + g]; }
        uint2 v0 = bsp[(size_t)ia * 16 + q];
        uint2 v1 = bsp[(size_t)ib * 16 + q];
        float2 l0 = __half22float2(*(const __half2*)&v0.x);
        float2 h0 = __half22float2(*(const __half2*)&v0.y);
        float2 l1 = __half22float2(*(const __half2*)&v1.x);
        float2 h1 = __half22float2(*(const __half2*)&v1.y);
        acc4.x += l0.x + l1.x;
        acc4.y += l0.y + l1.y;
        acc4.z += h0.x + h1.x;
        acc4.w += h0.y + h1.y;
        ia = na; ib = nb; j = jn;
    }
    int last = start + deg - 1;
    for (; j < deg; j += 4) {
        int idx = start + j + g;
        int r = csr[min(idx, last)];
        uint2 v = bsp[(size_t)r * 16 + q];
        float2 lo = __half22float2(*(const __half2*)&v.x);
        float2 hi = __half22float2(*(const __half2*)&v.y);
        float m = (j + g < deg) ? 1.f : 0.f;
        acc4.x = fmaf(lo.x, m, acc4.x);
        acc4.y = fmaf(lo.y, m, acc4.y);
        acc4.z = fmaf(hi.x, m, acc4.z);
        acc4.w = fmaf(hi.y, m, acc4.w);
    }

    acc4.x += __shfl_xor(acc4.x, 16, 64);
    acc4.y += __shfl_xor(acc4.y, 16, 64);
    acc4.z += __shfl_xor(acc4.z, 16, 64);
    acc4.w += __shfl_xor(acc4.w, 16, 64);
    acc4.x += __shfl_xor(acc4.x, 32, 64);
    acc4.y += __shfl_xor(acc4.y, 32, 64);
    acc4.z += __shfl_xor(acc4.z, 32, 64);
    acc4.w += __shfl_xor(acc4.w, 32, 64);

    float d = dis[wid];
    acc4.x *= d; acc4.y *= d; acc4.z *= d; acc4.w *= d;

    int src = lane >> 2;
    float t0 = __shfl(acc4.x, src, 64);
    float t1 = __shfl(acc4.y, src, 64);
    float t2 = __shfl(acc4.z, src, 64);
    float t3 = __shfl(acc4.w, src, 64);
    int c = lane & 3;
    float acc = (c == 0) ? t0 : (c == 1) ? t1 : (c == 2) ? t2 : t3;

    int fh = lane & 15;
    float a0 = __shfl(acc, fh, 64);
    float a1 = __shfl(acc, 16 + fh, 64);
    float a2 = __shfl(acc, 32 + fh, 64);
    float a3 = __shfl(acc, 48 + fh, 64);
    const float* wn = wcomb + (size_t)wid * 32;
    int hd = lane >> 4;
    float s1 = bias[lane];
    float s2v = bias[64 + lane];
    s1 = fmaf(wn[hd * 4 + 0], a0, s1);
    s1 = fmaf(wn[hd * 4 + 1], a1, s1);
    s1 = fmaf(wn[hd * 4 + 2], a2, s1);
    s1 = fmaf(wn[hd * 4 + 3], a3, s1);
    s2v = fmaf(wn[(4 + hd) * 4 + 0], a0, s2v);
    s2v = fmaf(wn[(4 + hd) * 4 + 1], a1, s2v);
    s2v = fmaf(wn[(4 + hd) * 4 + 2], a2, s2v);
    s2v = fmaf(wn[(4 + hd) * 4 + 3], a3, s2v);

    if (!LAYER2) {
        s1 = fmaxf(s1, 0.f);
        s2v = fmaxf(s2v, 0.f);
        h[(size_t)wid * 128 + lane] = s1;
        h[(size_t)wid * 128 + 64 + lane] = s2v;
    } else {
        float r0 = s1 * Wcls[lane * 2 + 0] + s2v * Wcls[(64 + lane) * 2 + 0];
        float r1 = s1 * Wcls[lane * 2 + 1] + s2v * Wcls[(64 + lane) * 2 + 1];
        float r2 = s1 * Wcls[(128 + lane) * 2 + 0] + s2v * Wcls[(192 + lane) * 2 + 0];
        float r3 = s1 * Wcls[(128 + lane) * 2 + 1] + s2v * Wcls[(192 + lane) * 2 + 1];
#pragma unroll
        for (int off = 32; off; off >>= 1) {
            r0 += __shfl_xor(r0, off, 64);
            r1 += __shfl_xor(r1, off, 64);
            r2 += __shfl_xor(r2, off, 64);
            r3 += __shfl_xor(r3, off, 64);
        }
        if (lane == 0) {
            p[wid * 4 + 0] = r0 + bcls[0];
            p[wid * 4 + 1] = r1 + bcls[1];
            p[wid * 4 + 2] = r2;
            p[wid * 4 + 3] = r3;
        }
    }
}

// ---------------- edge output: 2 edges/thread ----------------
__global__ void k_edge(const int* __restrict__ ei, const float* __restrict__ p,
                       float* __restrict__ out)
{
    int t = blockIdx.x * blockDim.x + threadIdx.x;
    if (t >= EE / 2) return;
    int2 rr = *(const int2*)(ei + 2 * t);
    int2 cc = *(const int2*)(ei + EE + 2 * t);
    float2 pt0 = *(const float2*)(p + rr.x * 4);
    float2 pt1 = *(const float2*)(p + rr.y * 4);
    float2 pb0 = *(const float2*)(p + cc.x * 4 + 2);
    float2 pb1 = *(const float2*)(p + cc.y * 4 + 2);
    float4 o;
    o.x = pt0.x + pb0.x;
    o.y = pt0.y + pb0.y;
    o.z = pt1.x + pb1.x;
    o.w = pt1.y + pb1.y;
    *(float4*)(out + (size_t)t * 4) = o;
}

extern "C" void kernel_launch(void* const* d_in, const int* in_sizes, int n_in,
                              void* d_out, int out_size, void* d_ws, size_t ws_size,
                              hipStream_t stream) {
    const float* x    = (const float*)d_in[0];
    const int*   ei   = (const int*)d_in[1];
    const float* Wb1  = (const float*)d_in[2];
    const float* Wc1  = (const float*)d_in[3];
    const float* bc1  = (const float*)d_in[4];
    const float* b1   = (const float*)d_in[5];
    const float* Wb2  = (const float*)d_in[6];
    const float* Wc2  = (const float*)d_in[7];
    const float* bc2  = (const float*)d_in[8];
    const float* b2   = (const float*)d_in[9];
    const float* Wcls = (const float*)d_in[10];
    const float* bcls = (const float*)d_in[11];
    float* out = (float*)d_out;

    char* ws = (char*)d_ws;
    size_t off = 0;
    auto alloc = [&](size_t bytes) {
        void* pp = ws + off;
        off += (bytes + 15) & ~(size_t)15;
        return pp;
    };

    float*    dis    = (float*)alloc(50048 * 4);
    __half*   bsh    = (__half*)alloc((size_t)NN * 64 * 2);
    float*    wcomb  = (float*)alloc((size_t)NN * 32 * 4);
    float*    h      = (float*)alloc((size_t)NN * 128 * 4);
    float*    p      = (float*)alloc((size_t)NN * 4 * 4);
    int*      cnt    = (int*)alloc(50048 * 4);
    int*      starts = (int*)alloc(50048 * 4);
    int2*     sd     = (int2*)alloc((size_t)50048 * 8);
    int*      csr    = (int*)alloc((size_t)EE * 4);
    unsigned* pk     = (unsigned*)alloc((size_t)EE * 4);

    const int B = 256;
    int gN   = (NN + B - 1) / B;   // 196
    int gN64 = (NN * 64) / B;      // 12500
    dim3 gG(gN, 3);

    // CSR build (shared by both layers)
    hipMemsetAsync(cnt, 0, NN * sizeof(int), stream);
    k_count<<<NB_CNT, B, 0, stream>>>(ei, cnt, pk);
    k_scan<<<gN, B, 0, stream>>>(cnt, dis, sd, starts, NN);
    k_fill<<<NCHUNK * NWIN, B, 0, stream>>>(ei, pk, starts, csr);

    // conv1
    k_gemm<<<gG, B, 0, stream>>>(x, Wb1, Wc1, bc1, dis, bsh, wcomb, NN);
    k_agg<0><<<gN64, B, 0, stream>>>(csr, sd, bsh, dis, wcomb, b1, h,
                                     Wcls, bcls, p, NN);

    // conv2 (+ fused edge-cls projection)
    k_gemm<<<gG, B, 0, stream>>>(h, Wb2, Wc2, bc2, dis, bsh, wcomb, NN);
    k_agg<1><<<gN64, B, 0, stream>>>(csr, sd, bsh, dis, wcomb, b2, h,
                                     Wcls, bcls, p, NN);

    // edge output
    k_edge<<<NB_E2, B, 0, stream>>>(ei, p, out);
}

// Round 7
// 265.648 us; speedup vs baseline: 1.0587x; 1.0564x over previous
//
#include <hip/hip_runtime.h>
#include <hip/hip_fp16.h>

#define NN 50000
#define NNP 50048        // padded node count for table rows
#define EE 800000
#define CH 32            // count chunks (25000 edges each)
#define CHE (EE / CH)    // 25000
#define NB_E2 1563       // ceil(400000/256): 2 edges/thread grids (k_edge)
#define NWIN 4           // windows (XCD pairs): csr seg ~800KB fits per-XCD L2
#define WIN 12500        // node-window per slot (4 * 12500 = 50000)
#define EPB 1024         // edges per fill chunk (256 thr x 4)
#define NCHUNK 782       // ceil(800000/1024)

// ---------------- windowed LDS count: NO device atomics ----------------
// Grid = CH*NWIN blocks. Block (c,w): LDS-histogram chunk c's cols in window w,
// assign per-chunk local rank via LDS atomicAdd (stays on-CU), pack
// pk[e] = col(16) | chunk(5)@16 | lrank(11)@21, flush histogram slice coalesced
// to part[c][w*WIN..]. Replaces 800K device atomics (44us, 28MB HBM RMW traffic).
__global__ __launch_bounds__(256) void k_count(
    const int* __restrict__ ei, unsigned* __restrict__ pk, int* __restrict__ part)
{
    __shared__ int hist[WIN];   // 50KB
    int c = blockIdx.x >> 2;
    int w = blockIdx.x & 3;
    int tid = threadIdx.x;
    for (int i = tid; i < WIN; i += 256) hist[i] = 0;
    __syncthreads();
    int e0 = c * CHE;
    unsigned lo = w * WIN;
    const int* cols = ei + EE + e0;
    for (int i = tid; i < CHE / 4; i += 256) {
        int4 cc = *(const int4*)(cols + i * 4);
        unsigned d;
        d = (unsigned)cc.x - lo;
        if (d < WIN) {
            int r = atomicAdd(&hist[d], 1);
            pk[e0 + i * 4 + 0] = (unsigned)cc.x | ((unsigned)c << 16) | ((unsigned)r << 21);
        }
        d = (unsigned)cc.y - lo;
        if (d < WIN) {
            int r = atomicAdd(&hist[d], 1);
            pk[e0 + i * 4 + 1] = (unsigned)cc.y | ((unsigned)c << 16) | ((unsigned)r << 21);
        }
        d = (unsigned)cc.z - lo;
        if (d < WIN) {
            int r = atomicAdd(&hist[d], 1);
            pk[e0 + i * 4 + 2] = (unsigned)cc.z | ((unsigned)c << 16) | ((unsigned)r << 21);
        }
        d = (unsigned)cc.w - lo;
        if (d < WIN) {
            int r = atomicAdd(&hist[d], 1);
            pk[e0 + i * 4 + 3] = (unsigned)cc.w | ((unsigned)c << 16) | ((unsigned)r << 21);
        }
    }
    __syncthreads();
    int* pc = part + (size_t)c * NNP + lo;
    for (int i = tid; i < WIN; i += 256) pc[i] = hist[i];
}

// ---------------- reduce partials -> cnt + dis ----------------
__global__ void k_reduce(const int* __restrict__ part, int* __restrict__ cnt,
                         float* __restrict__ dis) {
    int i = blockIdx.x * 256 + threadIdx.x;
    if (i >= NN) return;
    int v = 0;
#pragma unroll
    for (int c = 0; c < CH; c++) v += part[(size_t)c * NNP + i];
    cnt[i] = v;
    dis[i] = rsqrtf((float)v + 1.0f);  // +1 self loop
}

// ---------------- scan: starts + sd + per-chunk base table ----------------
// chunkstart[c][n] = starts[n] + sum_{c'<c} part[c'][n]  (folds starts lookup)
__global__ void k_scan(const int* __restrict__ cnt, const int* __restrict__ part,
                       int2* __restrict__ sd, int* __restrict__ chunkstart, int n) {
    __shared__ int s[256];
    int tid = threadIdx.x, b = blockIdx.x;
    int i = b * 256 + tid;
    int v = (i < n) ? cnt[i] : 0;
    s[tid] = v;
    __syncthreads();
    for (int off = 1; off < 256; off <<= 1) {
        int t2 = (tid >= off) ? s[tid - off] : 0;
        __syncthreads();
        if (tid >= off) s[tid] += t2;
        __syncthreads();
    }
    int loc = s[tid] - v;   // block-local exclusive
    // global prefix: sum cnt over preceding blocks (L2-hit int4 reads)
    int lim = b * 256;
    int pre = 0;
    for (int j = tid * 4; j < lim; j += 1024) {
        int4 c4 = *(const int4*)(cnt + j);
        pre += c4.x + c4.y + c4.z + c4.w;
    }
    __syncthreads();
    s[tid] = pre;
    __syncthreads();
    for (int off = 128; off; off >>= 1) {
        if (tid < off) s[tid] += s[tid + off];
        __syncthreads();
    }
    int boff = s[0];
    if (i < n) {
        int st = loc + boff;
        sd[i] = make_int2(st, v);
        int cs = st;
#pragma unroll
        for (int c = 0; c < CH; c++) {
            chunkstart[(size_t)c * NNP + i] = cs;
            cs += part[(size_t)c * NNP + i];
        }
    }
}

// ---------------- CSR fill: atomic-free, windowed scatter, packed reads ----------------
// pos = chunkstart[chunk][col] + lrank; window w on XCDs {w, w+4} (blockIdx%4).
__global__ __launch_bounds__(256) void k_fill(
    const int* __restrict__ ei, const unsigned* __restrict__ pk,
    const int* __restrict__ chunkstart, int* __restrict__ csr)
{
    int w = blockIdx.x & (NWIN - 1);
    int chunk = blockIdx.x >> 2;
    int base = chunk * EPB + threadIdx.x * 4;
    unsigned lo = w * WIN;
    if (base + 3 < EE) {
        int4 rr = *(const int4*)(ei + base);
        uint4 pp = *(const uint4*)(pk + base);
        unsigned c0 = pp.x & 0xffffu, c1 = pp.y & 0xffffu;
        unsigned c2 = pp.z & 0xffffu, c3 = pp.w & 0xffffu;
        if (c0 - lo < WIN) csr[chunkstart[(size_t)((pp.x >> 16) & 31u) * NNP + c0] + (pp.x >> 21)] = rr.x;
        if (c1 - lo < WIN) csr[chunkstart[(size_t)((pp.y >> 16) & 31u) * NNP + c1] + (pp.y >> 21)] = rr.y;
        if (c2 - lo < WIN) csr[chunkstart[(size_t)((pp.z >> 16) & 31u) * NNP + c2] + (pp.z >> 21)] = rr.z;
        if (c3 - lo < WIN) csr[chunkstart[(size_t)((pp.w >> 16) & 31u) * NNP + c3] + (pp.w >> 21)] = rr.w;
    } else {
        for (int e = 0; e < 4; e++) {
            int t = base + e;
            if (t < EE) {
                unsigned pv = pk[t];
                unsigned cgl = pv & 0xffffu;
                if (cgl - lo < WIN)
                    csr[chunkstart[(size_t)((pv >> 16) & 31u) * NNP + cgl] + (pv >> 21)] = ei[t];
            }
        }
    }
}

// ---------------- GEMM: LDS-staged x, thread-per-row, W via scalar cache ----------------
__global__ __launch_bounds__(256) void k_gemm(
    const float* __restrict__ x, const float* __restrict__ Wb,
    const float* __restrict__ Wc, const float* __restrict__ bc,
    const float* __restrict__ dis,
    __half* __restrict__ bsh, float* __restrict__ wcomb, int n)
{
    __shared__ float xt[32 * 257];  // transposed tile: xt[k][row]
    int tid = threadIdx.x;
    int grp = blockIdx.y;
    int row0 = blockIdx.x * 256;
    int row = row0 + tid;
    bool valid = row < n;

    const float* W = (grp < 2) ? (Wb + grp * 32) : Wc;
    const int ldw = (grp < 2) ? 64 : 32;

    float acc[32];
#pragma unroll
    for (int c = 0; c < 32; c++) acc[c] = 0.f;

    for (int s = 0; s < 4; s++) {
        int base_k = s * 32;
        float4 v[8];
#pragma unroll
        for (int i = 0; i < 8; i++) {
            int idx = i * 256 + tid;
            int r = idx >> 3;
            int k4 = idx & 7;
            int gr = row0 + r;
            v[i] = (gr < n) ? *(const float4*)(x + (size_t)gr * 128 + base_k + k4 * 4)
                            : make_float4(0.f, 0.f, 0.f, 0.f);
        }
        __syncthreads();
#pragma unroll
        for (int i = 0; i < 8; i++) {
            int idx = i * 256 + tid;
            int r = idx >> 3;
            int k4 = idx & 7;
            xt[(k4 * 4 + 0) * 257 + r] = v[i].x;
            xt[(k4 * 4 + 1) * 257 + r] = v[i].y;
            xt[(k4 * 4 + 2) * 257 + r] = v[i].z;
            xt[(k4 * 4 + 3) * 257 + r] = v[i].w;
        }
        __syncthreads();

        const float* Ws = W + base_k * ldw;
#pragma unroll 8
        for (int k = 0; k < 32; k++) {
            float xs = xt[k * 257 + tid];
            const float* wk = Ws + k * ldw;
#pragma unroll
            for (int c = 0; c < 32; c++) acc[c] = fmaf(xs, wk[c], acc[c]);
        }
    }

    if (!valid) return;
    if (grp < 2) {
        float d = dis[row];
        __half2 hh[16];
#pragma unroll
        for (int c = 0; c < 16; c++)
            hh[c] = __floats2half2_rn(acc[2 * c] * d, acc[2 * c + 1] * d);
        uint4* bo = (uint4*)(bsh + (size_t)row * 64 + grp * 32);
        const uint4* src = (const uint4*)hh;
#pragma unroll
        for (int c = 0; c < 4; c++) bo[c] = src[c];
    } else {
        float4* wo = (float4*)(wcomb + (size_t)row * 32);
#pragma unroll
        for (int c = 0; c < 8; c++)
            wo[c] = make_float4(acc[4*c] + bc[4*c], acc[4*c+1] + bc[4*c+1],
                                acc[4*c+2] + bc[4*c+2], acc[4*c+3] + bc[4*c+3]);
    }
}

// ---------------- fused aggregate (fp16 gather, pipelined, 8 edges/iter) + combine ----------------
template<int LAYER2>
__global__ __launch_bounds__(256) void k_agg(
    const int* __restrict__ csr, const int2* __restrict__ sd,
    const __half* __restrict__ bsh, const float* __restrict__ dis,
    const float* __restrict__ wcomb, const float* __restrict__ bias,
    float* __restrict__ h,
    const float* __restrict__ Wcls, const float* __restrict__ bcls,
    float* __restrict__ p, int n)
{
    int wid = (blockIdx.x * 256 + threadIdx.x) >> 6;
    int lane = threadIdx.x & 63;
    if (wid >= n) return;
    int2 s2 = sd[wid];
    int start = s2.x, deg = s2.y;
    int g = lane >> 4, q = lane & 15;

    const uint2* bsp = (const uint2*)bsh;
    float4 acc4 = make_float4(0.f, 0.f, 0.f, 0.f);
    if (g == 0) {  // self-loop term (pre-scaled)
        uint2 v = bsp[(size_t)wid * 16 + q];
        float2 lo = __half22float2(*(const __half2*)&v.x);
        float2 hi = __half22float2(*(const __half2*)&v.y);
        acc4 = make_float4(lo.x, lo.y, hi.x, hi.y);
    }

    int j = 0;
    int ia = 0, ib = 0;
    if (8 <= deg) { ia = csr[start + g]; ib = csr[start + 4 + g]; }
    while (j + 8 <= deg) {
        int jn = j + 8;
        int na = 0, nb = 0;
        if (jn + 8 <= deg) { na = csr[start + jn + g]; nb = csr[start + jn + 4 + g]; }
        uint2 v0 = bsp[(size_t)ia * 16 + q];
        uint2 v1 = bsp[(size_t)ib * 16 + q];
        float2 l0 = __half22float2(*(const __half2*)&v0.x);
        float2 h0 = __half22float2(*(const __half2*)&v0.y);
        float2 l1 = __half22float2(*(const __half2*)&v1.x);
        float2 h1 = __half22float2(*(const __half2*)&v1.y);
        acc4.x += l0.x + l1.x;
        acc4.y += l0.y + l1.y;
        acc4.z += h0.x + h1.x;
        acc4.w += h0.y + h1.y;
        ia = na; ib = nb; j = jn;
    }
    int last = start + deg - 1;
    for (; j < deg; j += 4) {
        int idx = start + j + g;
        int r = csr[min(idx, last)];
        uint2 v = bsp[(size_t)r * 16 + q];
        float2 lo = __half22float2(*(const __half2*)&v.x);
        float2 hi = __half22float2(*(const __half2*)&v.y);
        float m = (j + g < deg) ? 1.f : 0.f;
        acc4.x = fmaf(lo.x, m, acc4.x);
        acc4.y = fmaf(lo.y, m, acc4.y);
        acc4.z = fmaf(hi.x, m, acc4.z);
        acc4.w = fmaf(hi.y, m, acc4.w);
    }

    acc4.x += __shfl_xor(acc4.x, 16, 64);
    acc4.y += __shfl_xor(acc4.y, 16, 64);
    acc4.z += __shfl_xor(acc4.z, 16, 64);
    acc4.w += __shfl_xor(acc4.w, 16, 64);
    acc4.x += __shfl_xor(acc4.x, 32, 64);
    acc4.y += __shfl_xor(acc4.y, 32, 64);
    acc4.z += __shfl_xor(acc4.z, 32, 64);
    acc4.w += __shfl_xor(acc4.w, 32, 64);

    float d = dis[wid];
    acc4.x *= d; acc4.y *= d; acc4.z *= d; acc4.w *= d;

    int src = lane >> 2;
    float t0 = __shfl(acc4.x, src, 64);
    float t1 = __shfl(acc4.y, src, 64);
    float t2 = __shfl(acc4.z, src, 64);
    float t3 = __shfl(acc4.w, src, 64);
    int c = lane & 3;
    float acc = (c == 0) ? t0 : (c == 1) ? t1 : (c == 2) ? t2 : t3;

    int fh = lane & 15;
    float a0 = __shfl(acc, fh, 64);
    float a1 = __shfl(acc, 16 + fh, 64);
    float a2 = __shfl(acc, 32 + fh, 64);
    float a3 = __shfl(acc, 48 + fh, 64);
    const float* wn = wcomb + (size_t)wid * 32;
    int hd = lane >> 4;
    float s1 = bias[lane];
    float s2v = bias[64 + lane];
    s1 = fmaf(wn[hd * 4 + 0], a0, s1);
    s1 = fmaf(wn[hd * 4 + 1], a1, s1);
    s1 = fmaf(wn[hd * 4 + 2], a2, s1);
    s1 = fmaf(wn[hd * 4 + 3], a3, s1);
    s2v = fmaf(wn[(4 + hd) * 4 + 0], a0, s2v);
    s2v = fmaf(wn[(4 + hd) * 4 + 1], a1, s2v);
    s2v = fmaf(wn[(4 + hd) * 4 + 2], a2, s2v);
    s2v = fmaf(wn[(4 + hd) * 4 + 3], a3, s2v);

    if (!LAYER2) {
        s1 = fmaxf(s1, 0.f);
        s2v = fmaxf(s2v, 0.f);
        h[(size_t)wid * 128 + lane] = s1;
        h[(size_t)wid * 128 + 64 + lane] = s2v;
    } else {
        float r0 = s1 * Wcls[lane * 2 + 0] + s2v * Wcls[(64 + lane) * 2 + 0];
        float r1 = s1 * Wcls[lane * 2 + 1] + s2v * Wcls[(64 + lane) * 2 + 1];
        float r2 = s1 * Wcls[(128 + lane) * 2 + 0] + s2v * Wcls[(192 + lane) * 2 + 0];
        float r3 = s1 * Wcls[(128 + lane) * 2 + 1] + s2v * Wcls[(192 + lane) * 2 + 1];
#pragma unroll
        for (int off = 32; off; off >>= 1) {
            r0 += __shfl_xor(r0, off, 64);
            r1 += __shfl_xor(r1, off, 64);
            r2 += __shfl_xor(r2, off, 64);
            r3 += __shfl_xor(r3, off, 64);
        }
        if (lane == 0) {
            p[wid * 4 + 0] = r0 + bcls[0];
            p[wid * 4 + 1] = r1 + bcls[1];
            p[wid * 4 + 2] = r2;
            p[wid * 4 + 3] = r3;
        }
    }
}

// ---------------- edge output: 2 edges/thread ----------------
__global__ void k_edge(const int* __restrict__ ei, const float* __restrict__ p,
                       float* __restrict__ out)
{
    int t = blockIdx.x * blockDim.x + threadIdx.x;
    if (t >= EE / 2) return;
    int2 rr = *(const int2*)(ei + 2 * t);
    int2 cc = *(const int2*)(ei + EE + 2 * t);
    float2 pt0 = *(const float2*)(p + rr.x * 4);
    float2 pt1 = *(const float2*)(p + rr.y * 4);
    float2 pb0 = *(const float2*)(p + cc.x * 4 + 2);
    float2 pb1 = *(const float2*)(p + cc.y * 4 + 2);
    float4 o;
    o.x = pt0.x + pb0.x;
    o.y = pt0.y + pb0.y;
    o.z = pt1.x + pb1.x;
    o.w = pt1.y + pb1.y;
    *(float4*)(out + (size_t)t * 4) = o;
}

extern "C" void kernel_launch(void* const* d_in, const int* in_sizes, int n_in,
                              void* d_out, int out_size, void* d_ws, size_t ws_size,
                              hipStream_t stream) {
    const float* x    = (const float*)d_in[0];
    const int*   ei   = (const int*)d_in[1];
    const float* Wb1  = (const float*)d_in[2];
    const float* Wc1  = (const float*)d_in[3];
    const float* bc1  = (const float*)d_in[4];
    const float* b1   = (const float*)d_in[5];
    const float* Wb2  = (const float*)d_in[6];
    const float* Wc2  = (const float*)d_in[7];
    const float* bc2  = (const float*)d_in[8];
    const float* b2   = (const float*)d_in[9];
    const float* Wcls = (const float*)d_in[10];
    const float* bcls = (const float*)d_in[11];
    float* out = (float*)d_out;

    char* ws = (char*)d_ws;
    size_t off = 0;
    auto alloc = [&](size_t bytes) {
        void* pp = ws + off;
        off += (bytes + 15) & ~(size_t)15;
        return pp;
    };

    float*    dis    = (float*)alloc(50048 * 4);
    __half*   bsh    = (__half*)alloc((size_t)NN * 64 * 2);
    float*    wcomb  = (float*)alloc((size_t)NN * 32 * 4);
    float*    h      = (float*)alloc((size_t)NN * 128 * 4);
    float*    p      = (float*)alloc((size_t)NN * 4 * 4);
    int*      cnt    = (int*)alloc(50048 * 4);
    int2*     sd     = (int2*)alloc((size_t)50048 * 8);
    int*      csr    = (int*)alloc((size_t)EE * 4);
    unsigned* pk     = (unsigned*)alloc((size_t)EE * 4);
    int*      part   = (int*)alloc((size_t)CH * NNP * 4);       // 6.4 MB
    int*      chunkstart = (int*)alloc((size_t)CH * NNP * 4);   // 6.4 MB

    const int B = 256;
    int gN   = (NN + B - 1) / B;   // 196
    int gN64 = (NN * 64) / B;      // 12500
    dim3 gG(gN, 3);

    // CSR build (shared by both layers) — no memset, no device atomics
    k_count<<<CH * NWIN, B, 0, stream>>>(ei, pk, part);
    k_reduce<<<gN, B, 0, stream>>>(part, cnt, dis);
    k_scan<<<gN, B, 0, stream>>>(cnt, part, sd, chunkstart, NN);
    k_fill<<<NCHUNK * NWIN, B, 0, stream>>>(ei, pk, chunkstart, csr);

    // conv1
    k_gemm<<<gG, B, 0, stream>>>(x, Wb1, Wc1, bc1, dis, bsh, wcomb, NN);
    k_agg<0><<<gN64, B, 0, stream>>>(csr, sd, bsh, dis, wcomb, b1, h,
                                     Wcls, bcls, p, NN);

    // conv2 (+ fused edge-cls projection)
    k_gemm<<<gG, B, 0, stream>>>(h, Wb2, Wc2, bc2, dis, bsh, wcomb, NN);
    k_agg<1><<<gN64, B, 0, stream>>>(csr, sd, bsh, dis, wcomb, b2, h,
                                     Wcls, bcls, p, NN);

    // edge output
    k_edge<<<NB_E2, B, 0, stream>>>(ei, p, out);
}

// Round 8
// 263.571 us; speedup vs baseline: 1.0670x; 1.0079x over previous
//
#include <hip/hip_runtime.h>
#include <hip/hip_fp16.h>

#define NN 50000
#define NNP 50048        // padded node count for table rows
#define EE 800000
#define CH 32            // count chunks (25000 edges each)
#define CHE (EE / CH)    // 25000
#define NB_E2 1563       // ceil(400000/256): 2 edges/thread grids (k_edge)
#define NWIN 4           // windows (XCD pairs): csr seg ~800KB fits per-XCD L2
#define WIN 12500        // node-window per slot (4 * 12500 = 50000)
#define EPB 1024         // edges per fill chunk (256 thr x 4)
#define NCHUNK 782       // ceil(800000/1024)

// ---------------- windowed LDS count: NO device atomics ----------------
__global__ __launch_bounds__(256) void k_count(
    const int* __restrict__ ei, unsigned* __restrict__ pk, int* __restrict__ part)
{
    __shared__ int hist[WIN];   // 50KB
    int c = blockIdx.x >> 2;
    int w = blockIdx.x & 3;
    int tid = threadIdx.x;
    for (int i = tid; i < WIN; i += 256) hist[i] = 0;
    __syncthreads();
    int e0 = c * CHE;
    unsigned lo = w * WIN;
    const int* cols = ei + EE + e0;
    for (int i = tid; i < CHE / 4; i += 256) {
        int4 cc = *(const int4*)(cols + i * 4);
        unsigned d;
        d = (unsigned)cc.x - lo;
        if (d < WIN) {
            int r = atomicAdd(&hist[d], 1);
            pk[e0 + i * 4 + 0] = (unsigned)cc.x | ((unsigned)c << 16) | ((unsigned)r << 21);
        }
        d = (unsigned)cc.y - lo;
        if (d < WIN) {
            int r = atomicAdd(&hist[d], 1);
            pk[e0 + i * 4 + 1] = (unsigned)cc.y | ((unsigned)c << 16) | ((unsigned)r << 21);
        }
        d = (unsigned)cc.z - lo;
        if (d < WIN) {
            int r = atomicAdd(&hist[d], 1);
            pk[e0 + i * 4 + 2] = (unsigned)cc.z | ((unsigned)c << 16) | ((unsigned)r << 21);
        }
        d = (unsigned)cc.w - lo;
        if (d < WIN) {
            int r = atomicAdd(&hist[d], 1);
            pk[e0 + i * 4 + 3] = (unsigned)cc.w | ((unsigned)c << 16) | ((unsigned)r << 21);
        }
    }
    __syncthreads();
    int* pc = part + (size_t)c * NNP + lo;
    for (int i = tid; i < WIN; i += 256) pc[i] = hist[i];
}

// ---------------- reduce partials -> cnt + dis ----------------
__global__ void k_reduce(const int* __restrict__ part, int* __restrict__ cnt,
                         float* __restrict__ dis) {
    int i = blockIdx.x * 256 + threadIdx.x;
    if (i >= NN) return;
    int v = 0;
#pragma unroll
    for (int c = 0; c < CH; c++) v += part[(size_t)c * NNP + i];
    cnt[i] = v;
    dis[i] = rsqrtf((float)v + 1.0f);  // +1 self loop
}

// ---------------- scan: starts + sd + per-chunk base table ----------------
__global__ void k_scan(const int* __restrict__ cnt, const int* __restrict__ part,
                       int2* __restrict__ sd, int* __restrict__ chunkstart, int n) {
    __shared__ int s[256];
    int tid = threadIdx.x, b = blockIdx.x;
    int i = b * 256 + tid;
    int v = (i < n) ? cnt[i] : 0;
    s[tid] = v;
    __syncthreads();
    for (int off = 1; off < 256; off <<= 1) {
        int t2 = (tid >= off) ? s[tid - off] : 0;
        __syncthreads();
        if (tid >= off) s[tid] += t2;
        __syncthreads();
    }
    int loc = s[tid] - v;   // block-local exclusive
    int lim = b * 256;
    int pre = 0;
    for (int j = tid * 4; j < lim; j += 1024) {
        int4 c4 = *(const int4*)(cnt + j);
        pre += c4.x + c4.y + c4.z + c4.w;
    }
    __syncthreads();
    s[tid] = pre;
    __syncthreads();
    for (int off = 128; off; off >>= 1) {
        if (tid < off) s[tid] += s[tid + off];
        __syncthreads();
    }
    int boff = s[0];
    if (i < n) {
        int st = loc + boff;
        sd[i] = make_int2(st, v);
        int cs = st;
#pragma unroll
        for (int c = 0; c < CH; c++) {
            chunkstart[(size_t)c * NNP + i] = cs;
            cs += part[(size_t)c * NNP + i];
        }
    }
}

// ---------------- CSR fill: atomic-free, windowed scatter, packed reads ----------------
__global__ __launch_bounds__(256) void k_fill(
    const int* __restrict__ ei, const unsigned* __restrict__ pk,
    const int* __restrict__ chunkstart, int* __restrict__ csr)
{
    int w = blockIdx.x & (NWIN - 1);
    int chunk = blockIdx.x >> 2;
    int base = chunk * EPB + threadIdx.x * 4;
    unsigned lo = w * WIN;
    if (base + 3 < EE) {
        int4 rr = *(const int4*)(ei + base);
        uint4 pp = *(const uint4*)(pk + base);
        unsigned c0 = pp.x & 0xffffu, c1 = pp.y & 0xffffu;
        unsigned c2 = pp.z & 0xffffu, c3 = pp.w & 0xffffu;
        if (c0 - lo < WIN) csr[chunkstart[(size_t)((pp.x >> 16) & 31u) * NNP + c0] + (pp.x >> 21)] = rr.x;
        if (c1 - lo < WIN) csr[chunkstart[(size_t)((pp.y >> 16) & 31u) * NNP + c1] + (pp.y >> 21)] = rr.y;
        if (c2 - lo < WIN) csr[chunkstart[(size_t)((pp.z >> 16) & 31u) * NNP + c2] + (pp.z >> 21)] = rr.z;
        if (c3 - lo < WIN) csr[chunkstart[(size_t)((pp.w >> 16) & 31u) * NNP + c3] + (pp.w >> 21)] = rr.w;
    } else {
        for (int e = 0; e < 4; e++) {
            int t = base + e;
            if (t < EE) {
                unsigned pv = pk[t];
                unsigned cgl = pv & 0xffffu;
                if (cgl - lo < WIN)
                    csr[chunkstart[(size_t)((pv >> 16) & 31u) * NNP + cgl] + (pv >> 21)] = ei[t];
            }
        }
    }
}

// ---------------- GEMM: LDS-staged x, T14 software-pipelined (issue-early/write-late) ----------------
// Change vs r7: stage s+1's global loads are issued BEFORE stage s's FMA block,
// so HBM/L3 latency hides under the ~2048-cycle compute instead of stalling all
// waves at a vmcnt(0)+barrier drain (VALUBusy was 17% ~= pure FMA floor / 46us).
__global__ __launch_bounds__(256) void k_gemm(
    const float* __restrict__ x, const float* __restrict__ Wb,
    const float* __restrict__ Wc, const float* __restrict__ bc,
    const float* __restrict__ dis,
    __half* __restrict__ bsh, float* __restrict__ wcomb, int n)
{
    __shared__ float xt[32 * 257];  // transposed tile: xt[k][row]
    int tid = threadIdx.x;
    int grp = blockIdx.y;
    int row0 = blockIdx.x * 256;
    int row = row0 + tid;
    bool valid = row < n;

    const float* W = (grp < 2) ? (Wb + grp * 32) : Wc;
    const int ldw = (grp < 2) ? 64 : 32;

    float acc[32];
#pragma unroll
    for (int c = 0; c < 32; c++) acc[c] = 0.f;

    float4 v[8];
    // prologue: issue stage-0 loads
#pragma unroll
    for (int i = 0; i < 8; i++) {
        int idx = i * 256 + tid;
        int r = idx >> 3;
        int k4 = idx & 7;
        int gr = row0 + r;
        v[i] = (gr < n) ? *(const float4*)(x + (size_t)gr * 128 + k4 * 4)
                        : make_float4(0.f, 0.f, 0.f, 0.f);
    }

    for (int s = 0; s < 4; s++) {
        __syncthreads();   // previous stage's xt reads complete
#pragma unroll
        for (int i = 0; i < 8; i++) {
            int idx = i * 256 + tid;
            int r = idx >> 3;
            int k4 = idx & 7;
            xt[(k4 * 4 + 0) * 257 + r] = v[i].x;
            xt[(k4 * 4 + 1) * 257 + r] = v[i].y;
            xt[(k4 * 4 + 2) * 257 + r] = v[i].z;
            xt[(k4 * 4 + 3) * 257 + r] = v[i].w;
        }
        __syncthreads();

        if (s < 3) {       // issue next stage's loads; they fly under the FMA block
            int base_k = (s + 1) * 32;
#pragma unroll
            for (int i = 0; i < 8; i++) {
                int idx = i * 256 + tid;
                int r = idx >> 3;
                int k4 = idx & 7;
                int gr = row0 + r;
                v[i] = (gr < n) ? *(const float4*)(x + (size_t)gr * 128 + base_k + k4 * 4)
                                : make_float4(0.f, 0.f, 0.f, 0.f);
            }
        }

        const float* Ws = W + s * 32 * ldw;
#pragma unroll 8
        for (int k = 0; k < 32; k++) {
            float xs = xt[k * 257 + tid];
            const float* wk = Ws + k * ldw;
#pragma unroll
            for (int c = 0; c < 32; c++) acc[c] = fmaf(xs, wk[c], acc[c]);
        }
    }

    if (!valid) return;
    if (grp < 2) {
        float d = dis[row];
        __half2 hh[16];
#pragma unroll
        for (int c = 0; c < 16; c++)
            hh[c] = __floats2half2_rn(acc[2 * c] * d, acc[2 * c + 1] * d);
        uint4* bo = (uint4*)(bsh + (size_t)row * 64 + grp * 32);
        const uint4* src = (const uint4*)hh;
#pragma unroll
        for (int c = 0; c < 4; c++) bo[c] = src[c];
    } else {
        float4* wo = (float4*)(wcomb + (size_t)row * 32);
#pragma unroll
        for (int c = 0; c < 8; c++)
            wo[c] = make_float4(acc[4*c] + bc[4*c], acc[4*c+1] + bc[4*c+1],
                                acc[4*c+2] + bc[4*c+2], acc[4*c+3] + bc[4*c+3]);
    }
}

// ---------------- fused aggregate (fp16 gather, pipelined, 8 edges/iter) + combine ----------------
template<int LAYER2>
__global__ __launch_bounds__(256) void k_agg(
    const int* __restrict__ csr, const int2* __restrict__ sd,
    const __half* __restrict__ bsh, const float* __restrict__ dis,
    const float* __restrict__ wcomb, const float* __restrict__ bias,
    float* __restrict__ h,
    const float* __restrict__ Wcls, const float* __restrict__ bcls,
    float* __restrict__ p, int n)
{
    int wid = (blockIdx.x * 256 + threadIdx.x) >> 6;
    int lane = threadIdx.x & 63;
    if (wid >= n) return;
    int2 s2 = sd[wid];
    int start = s2.x, deg = s2.y;
    int g = lane >> 4, q = lane & 15;

    const uint2* bsp = (const uint2*)bsh;
    float4 acc4 = make_float4(0.f, 0.f, 0.f, 0.f);
    if (g == 0) {  // self-loop term (pre-scaled)
        uint2 v = bsp[(size_t)wid * 16 + q];
        float2 lo = __half22float2(*(const __half2*)&v.x);
        float2 hi = __half22float2(*(const __half2*)&v.y);
        acc4 = make_float4(lo.x, lo.y, hi.x, hi.y);
    }

    int j = 0;
    int ia = 0, ib = 0;
    if (8 <= deg) { ia = csr[start + g]; ib = csr[start + 4 + g]; }
    while (j + 8 <= deg) {
        int jn = j + 8;
        int na = 0, nb = 0;
        if (jn + 8 <= deg) { na = csr[start + jn + g]; nb = csr[start + jn + 4 + g]; }
        uint2 v0 = bsp[(size_t)ia * 16 + q];
        uint2 v1 = bsp[(size_t)ib * 16 + q];
        float2 l0 = __half22float2(*(const __half2*)&v0.x);
        float2 h0 = __half22float2(*(const __half2*)&v0.y);
        float2 l1 = __half22float2(*(const __half2*)&v1.x);
        float2 h1 = __half22float2(*(const __half2*)&v1.y);
        acc4.x += l0.x + l1.x;
        acc4.y += l0.y + l1.y;
        acc4.z += h0.x + h1.x;
        acc4.w += h0.y + h1.y;
        ia = na; ib = nb; j = jn;
    }
    int last = start + deg - 1;
    for (; j < deg; j += 4) {
        int idx = start + j + g;
        int r = csr[min(idx, last)];
        uint2 v = bsp[(size_t)r * 16 + q];
        float2 lo = __half22float2(*(const __half2*)&v.x);
        float2 hi = __half22float2(*(const __half2*)&v.y);
        float m = (j + g < deg) ? 1.f : 0.f;
        acc4.x = fmaf(lo.x, m, acc4.x);
        acc4.y = fmaf(lo.y, m, acc4.y);
        acc4.z = fmaf(hi.x, m, acc4.z);
        acc4.w = fmaf(hi.y, m, acc4.w);
    }

    acc4.x += __shfl_xor(acc4.x, 16, 64);
    acc4.y += __shfl_xor(acc4.y, 16, 64);
    acc4.z += __shfl_xor(acc4.z, 16, 64);
    acc4.w += __shfl_xor(acc4.w, 16, 64);
    acc4.x += __shfl_xor(acc4.x, 32, 64);
    acc4.y += __shfl_xor(acc4.y, 32, 64);
    acc4.z += __shfl_xor(acc4.z, 32, 64);
    acc4.w += __shfl_xor(acc4.w, 32, 64);

    float d = dis[wid];
    acc4.x *= d; acc4.y *= d; acc4.z *= d; acc4.w *= d;

    int src = lane >> 2;
    float t0 = __shfl(acc4.x, src, 64);
    float t1 = __shfl(acc4.y, src, 64);
    float t2 = __shfl(acc4.z, src, 64);
    float t3 = __shfl(acc4.w, src, 64);
    int c = lane & 3;
    float acc = (c == 0) ? t0 : (c == 1) ? t1 : (c == 2) ? t2 : t3;

    int fh = lane & 15;
    float a0 = __shfl(acc, fh, 64);
    float a1 = __shfl(acc, 16 + fh, 64);
    float a2 = __shfl(acc, 32 + fh, 64);
    float a3 = __shfl(acc, 48 + fh, 64);
    const float* wn = wcomb + (size_t)wid * 32;
    int hd = lane >> 4;
    float s1 = bias[lane];
    float s2v = bias[64 + lane];
    s1 = fmaf(wn[hd * 4 + 0], a0, s1);
    s1 = fmaf(wn[hd * 4 + 1], a1, s1);
    s1 = fmaf(wn[hd * 4 + 2], a2, s1);
    s1 = fmaf(wn[hd * 4 + 3], a3, s1);
    s2v = fmaf(wn[(4 + hd) * 4 + 0], a0, s2v);
    s2v = fmaf(wn[(4 + hd) * 4 + 1], a1, s2v);
    s2v = fmaf(wn[(4 + hd) * 4 + 2], a2, s2v);
    s2v = fmaf(wn[(4 + hd) * 4 + 3], a3, s2v);

    if (!LAYER2) {
        s1 = fmaxf(s1, 0.f);
        s2v = fmaxf(s2v, 0.f);
        h[(size_t)wid * 128 + lane] = s1;
        h[(size_t)wid * 128 + 64 + lane] = s2v;
    } else {
        float r0 = s1 * Wcls[lane * 2 + 0] + s2v * Wcls[(64 + lane) * 2 + 0];
        float r1 = s1 * Wcls[lane * 2 + 1] + s2v * Wcls[(64 + lane) * 2 + 1];
        float r2 = s1 * Wcls[(128 + lane) * 2 + 0] + s2v * Wcls[(192 + lane) * 2 + 0];
        float r3 = s1 * Wcls[(128 + lane) * 2 + 1] + s2v * Wcls[(192 + lane) * 2 + 1];
#pragma unroll
        for (int off = 32; off; off >>= 1) {
            r0 += __shfl_xor(r0, off, 64);
            r1 += __shfl_xor(r1, off, 64);
            r2 += __shfl_xor(r2, off, 64);
            r3 += __shfl_xor(r3, off, 64);
        }
        if (lane == 0) {
            p[wid * 4 + 0] = r0 + bcls[0];
            p[wid * 4 + 1] = r1 + bcls[1];
            p[wid * 4 + 2] = r2;
            p[wid * 4 + 3] = r3;
        }
    }
}

// ---------------- edge output: 2 edges/thread ----------------
__global__ void k_edge(const int* __restrict__ ei, const float* __restrict__ p,
                       float* __restrict__ out)
{
    int t = blockIdx.x * blockDim.x + threadIdx.x;
    if (t >= EE / 2) return;
    int2 rr = *(const int2*)(ei + 2 * t);
    int2 cc = *(const int2*)(ei + EE + 2 * t);
    float2 pt0 = *(const float2*)(p + rr.x * 4);
    float2 pt1 = *(const float2*)(p + rr.y * 4);
    float2 pb0 = *(const float2*)(p + cc.x * 4 + 2);
    float2 pb1 = *(const float2*)(p + cc.y * 4 + 2);
    float4 o;
    o.x = pt0.x + pb0.x;
    o.y = pt0.y + pb0.y;
    o.z = pt1.x + pb1.x;
    o.w = pt1.y + pb1.y;
    *(float4*)(out + (size_t)t * 4) = o;
}

extern "C" void kernel_launch(void* const* d_in, const int* in_sizes, int n_in,
                              void* d_out, int out_size, void* d_ws, size_t ws_size,
                              hipStream_t stream) {
    const float* x    = (const float*)d_in[0];
    const int*   ei   = (const int*)d_in[1];
    const float* Wb1  = (const float*)d_in[2];
    const float* Wc1  = (const float*)d_in[3];
    const float* bc1  = (const float*)d_in[4];
    const float* b1   = (const float*)d_in[5];
    const float* Wb2  = (const float*)d_in[6];
    const float* Wc2  = (const float*)d_in[7];
    const float* bc2  = (const float*)d_in[8];
    const float* b2   = (const float*)d_in[9];
    const float* Wcls = (const float*)d_in[10];
    const float* bcls = (const float*)d_in[11];
    float* out = (float*)d_out;

    char* ws = (char*)d_ws;
    size_t off = 0;
    auto alloc = [&](size_t bytes) {
        void* pp = ws + off;
        off += (bytes + 15) & ~(size_t)15;
        return pp;
    };

    float*    dis    = (float*)alloc(50048 * 4);
    __half*   bsh    = (__half*)alloc((size_t)NN * 64 * 2);
    float*    wcomb  = (float*)alloc((size_t)NN * 32 * 4);
    float*    h      = (float*)alloc((size_t)NN * 128 * 4);
    float*    p      = (float*)alloc((size_t)NN * 4 * 4);
    int*      cnt    = (int*)alloc(50048 * 4);
    int2*     sd     = (int2*)alloc((size_t)50048 * 8);
    int*      csr    = (int*)alloc((size_t)EE * 4);
    unsigned* pk     = (unsigned*)alloc((size_t)EE * 4);
    int*      part   = (int*)alloc((size_t)CH * NNP * 4);       // 6.4 MB
    int*      chunkstart = (int*)alloc((size_t)CH * NNP * 4);   // 6.4 MB

    const int B = 256;
    int gN   = (NN + B - 1) / B;   // 196
    int gN64 = (NN * 64) / B;      // 12500
    dim3 gG(gN, 3);

    // CSR build (shared by both layers) — no memset, no device atomics
    k_count<<<CH * NWIN, B, 0, stream>>>(ei, pk, part);
    k_reduce<<<gN, B, 0, stream>>>(part, cnt, dis);
    k_scan<<<gN, B, 0, stream>>>(cnt, part, sd, chunkstart, NN);
    k_fill<<<NCHUNK * NWIN, B, 0, stream>>>(ei, pk, chunkstart, csr);

    // conv1
    k_gemm<<<gG, B, 0, stream>>>(x, Wb1, Wc1, bc1, dis, bsh, wcomb, NN);
    k_agg<0><<<gN64, B, 0, stream>>>(csr, sd, bsh, dis, wcomb, b1, h,
                                     Wcls, bcls, p, NN);

    // conv2 (+ fused edge-cls projection)
    k_gemm<<<gG, B, 0, stream>>>(h, Wb2, Wc2, bc2, dis, bsh, wcomb, NN);
    k_agg<1><<<gN64, B, 0, stream>>>(csr, sd, bsh, dis, wcomb, b2, h,
                                     Wcls, bcls, p, NN);

    // edge output
    k_edge<<<NB_E2, B, 0, stream>>>(ei, p, out);
}